// Round 3
// baseline (1208.264 us; speedup 1.0000x reference)
//
#include <hip/hip_runtime.h>
#include <hip/hip_bf16.h>

#define IN_DIM 1024
#define DK 512
#define DV 512
#define NQ 8192
#define NKV 8192
#define BQ 32
#define BK 128

typedef _Float16 f16x8 __attribute__((ext_vector_type(8)));
typedef _Float16 f16x4 __attribute__((ext_vector_type(4)));
typedef float f32x4 __attribute__((ext_vector_type(4)));

// ---------------- projection: out = A @ W^T + b, stored f16 ----------------
// z=0: Q[N][DK] row-major; z=1: K[M][DK] row-major; z=2: Vt[DV][M] (transposed)
__global__ __launch_bounds__(256) void proj_kernel(
    const float* __restrict__ qin, const float* __restrict__ kin, const float* __restrict__ vin,
    const float* __restrict__ Wq, const float* __restrict__ bq,
    const float* __restrict__ Wk, const float* __restrict__ bk,
    const float* __restrict__ Wv, const float* __restrict__ bv,
    _Float16* __restrict__ Qb, _Float16* __restrict__ Kb, _Float16* __restrict__ Vt)
{
    const int z = blockIdx.z;
    const float* A  = (z == 0) ? qin : (z == 1) ? kin : vin;
    const float* W  = (z == 0) ? Wq  : (z == 1) ? Wk  : Wv;
    const float* bi = (z == 0) ? bq  : (z == 1) ? bk  : bv;

    __shared__ _Float16 As[128][72];
    __shared__ _Float16 Bs[128][72];

    const int tid = threadIdx.x;
    const int rowbase = blockIdx.y * 128;
    const int colbase = blockIdx.x * 128;
    const int wave = tid >> 6;
    const int lane = tid & 63;
    const int quad = lane >> 4;
    const int l16  = lane & 15;
    const int wrow = (wave & 1) * 64;
    const int wcol = (wave >> 1) * 64;

    f32x4 acc[4][4];
#pragma unroll
    for (int r = 0; r < 4; ++r)
#pragma unroll
        for (int c = 0; c < 4; ++c) acc[r][c] = (f32x4)(0.0f);

    for (int kc = 0; kc < IN_DIM / 64; ++kc) {
        __syncthreads();
#pragma unroll
        for (int i = 0; i < 8; ++i) {
            int idx = tid + i * 256;
            int row = idx >> 4;
            int c4  = idx & 15;
            float4 ga = *(const float4*)&A[(size_t)(rowbase + row) * IN_DIM + kc * 64 + c4 * 4];
            f16x4 pa;
            pa[0] = (_Float16)ga.x; pa[1] = (_Float16)ga.y;
            pa[2] = (_Float16)ga.z; pa[3] = (_Float16)ga.w;
            *(f16x4*)&As[row][c4 * 4] = pa;
            float4 gb = *(const float4*)&W[(size_t)(colbase + row) * IN_DIM + kc * 64 + c4 * 4];
            f16x4 pb;
            pb[0] = (_Float16)gb.x; pb[1] = (_Float16)gb.y;
            pb[2] = (_Float16)gb.z; pb[3] = (_Float16)gb.w;
            *(f16x4*)&Bs[row][c4 * 4] = pb;
        }
        __syncthreads();
#pragma unroll
        for (int ks = 0; ks < 2; ++ks) {
            f16x8 af[4], bfr[4];
#pragma unroll
            for (int r = 0; r < 4; ++r)
                af[r] = *(const f16x8*)&As[wrow + r * 16 + l16][ks * 32 + quad * 8];
#pragma unroll
            for (int c = 0; c < 4; ++c)
                bfr[c] = *(const f16x8*)&Bs[wcol + c * 16 + l16][ks * 32 + quad * 8];
#pragma unroll
            for (int r = 0; r < 4; ++r)
#pragma unroll
                for (int c = 0; c < 4; ++c)
                    acc[r][c] = __builtin_amdgcn_mfma_f32_16x16x32_f16(af[r], bfr[c], acc[r][c], 0, 0, 0);
        }
    }

    if (z < 2) {
        _Float16* outp = (z == 0) ? Qb : Kb;
#pragma unroll
        for (int c = 0; c < 4; ++c) {
            int col = colbase + wcol + c * 16 + l16;
            float bval = bi[col];
#pragma unroll
            for (int r = 0; r < 4; ++r)
#pragma unroll
                for (int g = 0; g < 4; ++g) {
                    int row = rowbase + wrow + r * 16 + quad * 4 + g;
                    outp[(size_t)row * DK + col] = (_Float16)(acc[r][c][g] + bval);
                }
        }
    } else {
#pragma unroll
        for (int c = 0; c < 4; ++c) {
            int col = colbase + wcol + c * 16 + l16;
            float bval = bi[col];
#pragma unroll
            for (int r = 0; r < 4; ++r) {
                int row0 = rowbase + wrow + r * 16 + quad * 4;
                f16x4 pk;
#pragma unroll
                for (int g = 0; g < 4; ++g) pk[g] = (_Float16)(acc[r][c][g] + bval);
                *(f16x4*)&Vt[(size_t)col * NKV + row0] = pk;
            }
        }
    }
}

// ------- flash attention, 4-wave blocks, no Q duplication, KV-split --------
// Wave w: S-phase -> q-band (w>>1)*16, key-band (w&1)*64 (4 key tiles).
//         PV-phase -> d_v band w*128 (8 tiles), all 32 q rows.
__global__ __launch_bounds__(256, 3) void flash_kernel(
    const _Float16* __restrict__ Qb, const _Float16* __restrict__ Kb,
    const _Float16* __restrict__ Vt, float* __restrict__ Opart,
    float* __restrict__ Mpart, float* __restrict__ Lpart,
    float* __restrict__ outp, int nsplit, int nchunks)
{
    __shared__ _Float16 Ps[BQ][BK + 8];   // 8704 B
    __shared__ float Smax[2][BQ];
    __shared__ float Ssum[2][BQ];
    __shared__ float row_m[2][BQ];
    __shared__ float row_l[2][BQ];
    __shared__ float row_alpha[BQ];

    const int tid  = threadIdx.x;
    const int w    = tid >> 6;
    const int lane = tid & 63;
    const int quad = lane >> 4;
    const int l16  = lane & 15;
    const int qb   = w >> 1;
    const int kb   = w & 1;
    const int qbase = blockIdx.x * BQ;
    const int keystart = blockIdx.y * nchunks * BK;

    // Q fragments for this wave's 16-row band only (64 VGPRs, loop-invariant)
    f16x8 qf[16];
    {
        const _Float16* qp = Qb + (size_t)(qbase + qb * 16 + l16) * DK + quad * 8;
#pragma unroll
        for (int ks = 0; ks < 16; ++ks) qf[ks] = *(const f16x8*)(qp + ks * 32);
    }

    if (tid < BQ) { row_m[0][tid] = -1e30f; row_l[0][tid] = 0.0f; }

    f32x4 oacc[2][8];
#pragma unroll
    for (int r = 0; r < 2; ++r)
#pragma unroll
        for (int c = 0; c < 8; ++c) oacc[r][c] = (f32x4)(0.0f);

    const _Float16* kbp = Kb + (size_t)(keystart + kb * 64 + l16) * DK + quad * 8;
    const _Float16* vbp = Vt + (size_t)(w * 128 + l16) * NKV + keystart + quad * 8;

    for (int ch = 0; ch < nchunks; ++ch) {
        const int par = ch & 1;

        // ---- S: 16 q x 64 keys for this wave (4 tiles)
        f32x4 s[4];
#pragma unroll
        for (int t = 0; t < 4; ++t) s[t] = (f32x4)(0.0f);
        const _Float16* kp = kbp + (size_t)ch * BK * DK;
#pragma unroll
        for (int ks = 0; ks < 16; ++ks) {
            f16x8 qv = qf[ks];
#pragma unroll
            for (int t = 0; t < 4; ++t) {
                f16x8 kf = *(const f16x8*)(kp + (size_t)t * 16 * DK + ks * 32);
                s[t] = __builtin_amdgcn_mfma_f32_16x16x32_f16(qv, kf, s[t], 0, 0, 0);
            }
        }

        // ---- per-row partial max: regs (4 tiles) then 16-lane shuffle tree
#pragma unroll
        for (int g = 0; g < 4; ++g) {
            float m = fmaxf(fmaxf(s[0][g], s[1][g]), fmaxf(s[2][g], s[3][g]));
#pragma unroll
            for (int msk = 1; msk < 16; msk <<= 1) m = fmaxf(m, __shfl_xor(m, msk));
            if (l16 == 0) Smax[kb][qb * 16 + quad * 4 + g] = m;
        }
        __syncthreads();

        // ---- finalize m (32 scalar threads)
        if (tid < BQ) {
            float m_old = row_m[par][tid];
            float m_new = fmaxf(fmaxf(Smax[0][tid], Smax[1][tid]), m_old);
            row_m[par ^ 1][tid] = m_new;
            row_alpha[tid] = __expf(m_old - m_new);
        }
        __syncthreads();

        // ---- exp, partial sums, P write (f16)
#pragma unroll
        for (int g = 0; g < 4; ++g) {
            const int row = qb * 16 + quad * 4 + g;
            float mn = row_m[par ^ 1][row];
            float p0 = __expf(s[0][g] - mn);
            float p1 = __expf(s[1][g] - mn);
            float p2 = __expf(s[2][g] - mn);
            float p3 = __expf(s[3][g] - mn);
            Ps[row][kb * 64 +      l16] = (_Float16)p0;
            Ps[row][kb * 64 + 16 + l16] = (_Float16)p1;
            Ps[row][kb * 64 + 32 + l16] = (_Float16)p2;
            Ps[row][kb * 64 + 48 + l16] = (_Float16)p3;
            float ts = (p0 + p1) + (p2 + p3);
#pragma unroll
            for (int msk = 1; msk < 16; msk <<= 1) ts += __shfl_xor(ts, msk);
            if (l16 == 0) Ssum[kb][row] = ts;
        }
        __syncthreads();

        // ---- l update (program-order safe: same 32 threads each chunk)
        if (tid < BQ)
            row_l[par ^ 1][tid] = row_l[par][tid] * row_alpha[tid]
                                  + Ssum[0][tid] + Ssum[1][tid];

        // ---- O rescale + PV over this wave's 128-wide d_v band
        float al[2][4];
#pragma unroll
        for (int r = 0; r < 2; ++r)
#pragma unroll
            for (int g = 0; g < 4; ++g) al[r][g] = row_alpha[r * 16 + quad * 4 + g];
#pragma unroll
        for (int r = 0; r < 2; ++r)
#pragma unroll
            for (int c = 0; c < 8; ++c)
#pragma unroll
                for (int g = 0; g < 4; ++g) oacc[r][c][g] *= al[r][g];

        const _Float16* vp = vbp + ch * BK;
#pragma unroll
        for (int ks = 0; ks < 4; ++ks) {
            f16x8 pf0 = *(const f16x8*)&Ps[l16][ks * 32 + quad * 8];
            f16x8 pf1 = *(const f16x8*)&Ps[16 + l16][ks * 32 + quad * 8];
#pragma unroll
            for (int c = 0; c < 8; ++c) {
                f16x8 vf = *(const f16x8*)(vp + (size_t)c * 16 * NKV + ks * 32);
                oacc[0][c] = __builtin_amdgcn_mfma_f32_16x16x32_f16(pf0, vf, oacc[0][c], 0, 0, 0);
                oacc[1][c] = __builtin_amdgcn_mfma_f32_16x16x32_f16(pf1, vf, oacc[1][c], 0, 0, 0);
            }
        }
    }

    __syncthreads();   // final row_l/row_m in buffer 0 (nchunks even)

    if (nsplit == 1) {
        const float norm = 0.044194173824159216f;
#pragma unroll
        for (int r = 0; r < 2; ++r)
#pragma unroll
            for (int g = 0; g < 4; ++g) {
                const int row = r * 16 + quad * 4 + g;
                const float sc = norm / row_l[0][row];
#pragma unroll
                for (int c = 0; c < 8; ++c)
                    outp[(size_t)(qbase + row) * DV + w * 128 + c * 16 + l16] = oacc[r][c][g] * sc;
            }
    } else {
        float* op = Opart + (size_t)(blockIdx.x * nsplit + blockIdx.y) * BQ * DV;
#pragma unroll
        for (int r = 0; r < 2; ++r)
#pragma unroll
            for (int g = 0; g < 4; ++g) {
                const int row = r * 16 + quad * 4 + g;
#pragma unroll
                for (int c = 0; c < 8; ++c)
                    op[(size_t)row * DV + w * 128 + c * 16 + l16] = oacc[r][c][g];
            }
        if (tid < BQ) {
            int idx = (blockIdx.x * nsplit + blockIdx.y) * BQ + tid;
            Mpart[idx] = row_m[0][tid];
            Lpart[idx] = row_l[0][tid];
        }
    }
}

// ---------------- combine KV-split partials -------------------------------
__global__ __launch_bounds__(512) void reduce_kernel(
    const float* __restrict__ Opart, const float* __restrict__ Mpart,
    const float* __restrict__ Lpart, float* __restrict__ outp, int nsplit)
{
    __shared__ float sc[4][BQ];
    __shared__ float rs[BQ];
    const int tid = threadIdx.x;
    const int qt = blockIdx.x;

    if (tid < BQ) {
        float M = -1e30f;
        for (int s = 0; s < nsplit; ++s)
            M = fmaxf(M, Mpart[(qt * nsplit + s) * BQ + tid]);
        float L = 0.0f;
        for (int s = 0; s < nsplit; ++s) {
            float e = __expf(Mpart[(qt * nsplit + s) * BQ + tid] - M);
            sc[s][tid] = e;
            L += Lpart[(qt * nsplit + s) * BQ + tid] * e;
        }
        rs[tid] = 0.044194173824159216f / L;
    }
    __syncthreads();

    const int row = tid >> 4;
    const int cb  = (tid & 15) * 4;
    const float* base = Opart + ((size_t)qt * nsplit * BQ + row) * DV + cb;
    float* ob = outp + ((size_t)(qt * BQ + row)) * DV + cb;
    const float r = rs[row];
#pragma unroll
    for (int i = 0; i < 8; ++i) {
        float4 o = make_float4(0.f, 0.f, 0.f, 0.f);
        for (int s = 0; s < nsplit; ++s) {
            float4 a = *(const float4*)(base + (size_t)s * BQ * DV + i * 64);
            float e = sc[s][row];
            o.x += a.x * e; o.y += a.y * e; o.z += a.z * e; o.w += a.w * e;
        }
        o.x *= r; o.y *= r; o.z *= r; o.w *= r;
        *(float4*)(ob + i * 64) = o;
    }
}

extern "C" void kernel_launch(void* const* d_in, const int* in_sizes, int n_in,
                              void* d_out, int out_size, void* d_ws, size_t ws_size,
                              hipStream_t stream) {
    const float* q  = (const float*)d_in[0];
    const float* k  = (const float*)d_in[1];
    const float* v  = (const float*)d_in[2];
    const float* Wq = (const float*)d_in[3];
    const float* bq = (const float*)d_in[4];
    const float* Wk = (const float*)d_in[5];
    const float* bk = (const float*)d_in[6];
    const float* Wv = (const float*)d_in[7];
    const float* bv = (const float*)d_in[8];

    _Float16* Qb = (_Float16*)d_ws;                 // 8 MB
    _Float16* Kb = Qb + (size_t)NQ * DK;            // 8 MB
    _Float16* Vt = Kb + (size_t)NKV * DK;           // 8 MB
    const size_t base = 3 * (size_t)NQ * DK * sizeof(_Float16);
    float* Mpart = (float*)((char*)d_ws + base);            // <=128 KB
    float* Lpart = Mpart + 4 * (NQ / BQ) * BQ;              // <=128 KB
    float* Opart = Lpart + 4 * (NQ / BQ) * BQ;
    const size_t per_split = (size_t)(NQ / BQ) * BQ * DV * sizeof(float);  // 16 MB

    int nsplit = 1;
    if (ws_size >= base + 262144 + 4 * per_split) nsplit = 4;
    else if (ws_size >= base + 262144 + 2 * per_split) nsplit = 2;
    const int nchunks = NKV / (nsplit * BK);
    float* outp = (float*)d_out;

    proj_kernel<<<dim3(DK / 128, NQ / 128, 3), 256, 0, stream>>>(
        q, k, v, Wq, bq, Wk, bk, Wv, bv, Qb, Kb, Vt);
    flash_kernel<<<dim3(NQ / BQ, nsplit), 256, 0, stream>>>(
        Qb, Kb, Vt, Opart, Mpart, Lpart, outp, nsplit, nchunks);
    if (nsplit > 1)
        reduce_kernel<<<dim3(NQ / BQ), 512, 0, stream>>>(Opart, Mpart, Lpart, outp, nsplit);
}

// Round 4
// 934.691 us; speedup vs baseline: 1.2927x; 1.2927x over previous
//
#include <hip/hip_runtime.h>
#include <hip/hip_bf16.h>

#define IN_DIM 1024
#define DK 512
#define DV 512
#define NQ 8192
#define NKV 8192
#define BQ 128
#define BK 64

typedef _Float16 f16x8 __attribute__((ext_vector_type(8)));
typedef _Float16 f16x4 __attribute__((ext_vector_type(4)));
typedef float f32x4 __attribute__((ext_vector_type(4)));

// ---------------- projection: out = A @ W^T + b, stored f16 ----------------
__global__ __launch_bounds__(256) void proj_kernel(
    const float* __restrict__ qin, const float* __restrict__ kin, const float* __restrict__ vin,
    const float* __restrict__ Wq, const float* __restrict__ bq,
    const float* __restrict__ Wk, const float* __restrict__ bk,
    const float* __restrict__ Wv, const float* __restrict__ bv,
    _Float16* __restrict__ Qb, _Float16* __restrict__ Kb, _Float16* __restrict__ Vt)
{
    const int z = blockIdx.z;
    const float* A  = (z == 0) ? qin : (z == 1) ? kin : vin;
    const float* W  = (z == 0) ? Wq  : (z == 1) ? Wk  : Wv;
    const float* bi = (z == 0) ? bq  : (z == 1) ? bk  : bv;

    __shared__ _Float16 As[128][72];
    __shared__ _Float16 Bs[128][72];

    const int tid = threadIdx.x;
    const int rowbase = blockIdx.y * 128;
    const int colbase = blockIdx.x * 128;
    const int wave = tid >> 6;
    const int lane = tid & 63;
    const int quad = lane >> 4;
    const int l16  = lane & 15;
    const int wrow = (wave & 1) * 64;
    const int wcol = (wave >> 1) * 64;

    f32x4 acc[4][4];
#pragma unroll
    for (int r = 0; r < 4; ++r)
#pragma unroll
        for (int c = 0; c < 4; ++c) acc[r][c] = (f32x4)(0.0f);

    for (int kc = 0; kc < IN_DIM / 64; ++kc) {
        __syncthreads();
#pragma unroll
        for (int i = 0; i < 8; ++i) {
            int idx = tid + i * 256;
            int row = idx >> 4;
            int c4  = idx & 15;
            float4 ga = *(const float4*)&A[(size_t)(rowbase + row) * IN_DIM + kc * 64 + c4 * 4];
            f16x4 pa;
            pa[0] = (_Float16)ga.x; pa[1] = (_Float16)ga.y;
            pa[2] = (_Float16)ga.z; pa[3] = (_Float16)ga.w;
            *(f16x4*)&As[row][c4 * 4] = pa;
            float4 gb = *(const float4*)&W[(size_t)(colbase + row) * IN_DIM + kc * 64 + c4 * 4];
            f16x4 pb;
            pb[0] = (_Float16)gb.x; pb[1] = (_Float16)gb.y;
            pb[2] = (_Float16)gb.z; pb[3] = (_Float16)gb.w;
            *(f16x4*)&Bs[row][c4 * 4] = pb;
        }
        __syncthreads();
#pragma unroll
        for (int ks = 0; ks < 2; ++ks) {
            f16x8 af[4], bfr[4];
#pragma unroll
            for (int r = 0; r < 4; ++r)
                af[r] = *(const f16x8*)&As[wrow + r * 16 + l16][ks * 32 + quad * 8];
#pragma unroll
            for (int c = 0; c < 4; ++c)
                bfr[c] = *(const f16x8*)&Bs[wcol + c * 16 + l16][ks * 32 + quad * 8];
#pragma unroll
            for (int r = 0; r < 4; ++r)
#pragma unroll
                for (int c = 0; c < 4; ++c)
                    acc[r][c] = __builtin_amdgcn_mfma_f32_16x16x32_f16(af[r], bfr[c], acc[r][c], 0, 0, 0);
        }
    }

    if (z < 2) {
        _Float16* outp = (z == 0) ? Qb : Kb;
#pragma unroll
        for (int c = 0; c < 4; ++c) {
            int col = colbase + wcol + c * 16 + l16;
            float bval = bi[col];
#pragma unroll
            for (int r = 0; r < 4; ++r)
#pragma unroll
                for (int g = 0; g < 4; ++g) {
                    int row = rowbase + wrow + r * 16 + quad * 4 + g;
                    outp[(size_t)row * DK + col] = (_Float16)(acc[r][c][g] + bval);
                }
        }
    } else {
#pragma unroll
        for (int c = 0; c < 4; ++c) {
            int col = colbase + wcol + c * 16 + l16;
            float bval = bi[col];
#pragma unroll
            for (int r = 0; r < 4; ++r) {
                int row0 = rowbase + wrow + r * 16 + quad * 4;
                f16x4 pk;
#pragma unroll
                for (int g = 0; g < 4; ++g) pk[g] = (_Float16)(acc[r][c][g] + bval);
                *(f16x4*)&Vt[(size_t)col * NKV + row0] = pk;
            }
        }
    }
}

// ---- flash attention: LDS-staged K/V with XOR swizzle, Q in registers ----
// 8 waves. S-phase: wave = (qb = w>>1 in 0..3 [32 q rows], kh = w&1 [256-k half]).
// PV-phase: wave = (qb, dvh = w&1 [256-dv half]); oacc = 32q x 256dv / wave.
// LDS: Ks 64KB (swizzled) | Vts 64KB (swizzled) | per-pair 8KB union
//   (Spart[8 tiles][quad][l16][4f32]  -> then Ps[32][72]f16 + alpha[32]f32)
__global__ __launch_bounds__(512, 2) void flash_kernel(
    const _Float16* __restrict__ Qb, const _Float16* __restrict__ Kb,
    const _Float16* __restrict__ Vt, float* __restrict__ Opart,
    float* __restrict__ Mpart, float* __restrict__ Lpart,
    float* __restrict__ outp, int nsplit, int nchunks)
{
    __shared__ __align__(16) char smem_[163840];
    char* KsB  = smem_;              // [64 keys][1024 B], col-chunk swizzle ^(key&7)
    char* VtsB = smem_ + 65536;      // [512 dv][128 B],  col-chunk swizzle ^(dv&7)
    char* uniB = smem_ + 131072;     // 4 pair regions x 8192 B

    const int tid  = threadIdx.x;
    const int w    = tid >> 6;
    const int lane = tid & 63;
    const int quad = lane >> 4;
    const int l16  = lane & 15;
    const int qb   = w >> 1;         // q-band (32 rows) for S and PV
    const int kh   = w & 1;          // k-half for S
    const int dvh  = w & 1;          // dv-half for PV
    const int qbase = blockIdx.x * BQ;
    const int keystart = blockIdx.y * nchunks * BK;
    char* pair = uniB + qb * 8192;

    // Q fragments: rows qb*32 + qt*16 + l16, k = kh*256 + step*32 + quad*8
    f16x8 qf[2][8];
#pragma unroll
    for (int qt = 0; qt < 2; ++qt) {
        const _Float16* qp = Qb + (size_t)(qbase + qb * 32 + qt * 16 + l16) * DK
                             + kh * 256 + quad * 8;
#pragma unroll
        for (int st = 0; st < 8; ++st) qf[qt][st] = *(const f16x8*)(qp + st * 32);
    }

    float mreg[2][4], lreg[2][4];
#pragma unroll
    for (int qt = 0; qt < 2; ++qt)
#pragma unroll
        for (int g = 0; g < 4; ++g) { mreg[qt][g] = -1e30f; lreg[qt][g] = 0.0f; }

    f32x4 oacc[2][16];
#pragma unroll
    for (int qt = 0; qt < 2; ++qt)
#pragma unroll
        for (int ct = 0; ct < 16; ++ct) oacc[qt][ct] = (f32x4)(0.0f);

    for (int ch = 0; ch < nchunks; ++ch) {
        const int kpos = keystart + ch * BK;

        // ---- stage K tile [64][512] f16 (global coalesced -> swizzled LDS)
#pragma unroll
        for (int i = 0; i < 8; ++i) {
            int u = tid + i * 512;
            int key = u >> 6, c8 = u & 63;
            uint4 d = *(const uint4*)&Kb[(size_t)(kpos + key) * DK + c8 * 8];
            *(uint4*)(KsB + key * 1024 + ((c8 ^ (key & 7)) << 4)) = d;
        }
        // ---- stage V tile Vt[512][64] f16
#pragma unroll
        for (int i = 0; i < 8; ++i) {
            int u = tid + i * 512;
            int dv = u >> 3, c8 = u & 7;
            uint4 d = *(const uint4*)&Vt[(size_t)dv * NKV + kpos + c8 * 8];
            *(uint4*)(VtsB + dv * 128 + ((c8 ^ (dv & 7)) << 4)) = d;
        }
        __syncthreads();   // B1: tiles ready (also: prev chunk fully consumed)

        // ---- S partial: 32 q x 64 keys over this wave's 256-k half
        f32x4 s[2][4];
#pragma unroll
        for (int qt = 0; qt < 2; ++qt)
#pragma unroll
            for (int kt = 0; kt < 4; ++kt) s[qt][kt] = (f32x4)(0.0f);
#pragma unroll
        for (int st = 0; st < 8; ++st) {
            f16x8 kf[4];
#pragma unroll
            for (int kt = 0; kt < 4; ++kt) {
                int key = kt * 16 + l16;
                int c8 = kh * 32 + st * 4 + quad;
                kf[kt] = *(const f16x8*)(KsB + key * 1024 + ((c8 ^ (key & 7)) << 4));
            }
#pragma unroll
            for (int qt = 0; qt < 2; ++qt)
#pragma unroll
                for (int kt = 0; kt < 4; ++kt)
                    s[qt][kt] = __builtin_amdgcn_mfma_f32_16x16x32_f16(qf[qt][st], kf[kt], s[qt][kt], 0, 0, 0);
        }

        if (kh == 0) {   // write partials for partner
#pragma unroll
            for (int qt = 0; qt < 2; ++qt)
#pragma unroll
                for (int kt = 0; kt < 4; ++kt)
                    *(f32x4*)(pair + (qt * 4 + kt) * 1024 + quad * 256 + l16 * 16) = s[qt][kt];
        }
        __syncthreads();   // B2

        if (kh == 1) {   // combine + online softmax for rows qb*32..+31
            f32x4 padd[2][4];
#pragma unroll
            for (int qt = 0; qt < 2; ++qt)
#pragma unroll
                for (int kt = 0; kt < 4; ++kt)
                    padd[qt][kt] = *(const f32x4*)(pair + (qt * 4 + kt) * 1024 + quad * 256 + l16 * 16);
#pragma unroll
            for (int qt = 0; qt < 2; ++qt)
#pragma unroll
                for (int kt = 0; kt < 4; ++kt) s[qt][kt] += padd[qt][kt];

#pragma unroll
            for (int qt = 0; qt < 2; ++qt)
#pragma unroll
                for (int g = 0; g < 4; ++g) {
                    float m = fmaxf(fmaxf(s[qt][0][g], s[qt][1][g]),
                                    fmaxf(s[qt][2][g], s[qt][3][g]));
#pragma unroll
                    for (int msk = 1; msk < 16; msk <<= 1) m = fmaxf(m, __shfl_xor(m, msk));
                    float m_new = fmaxf(mreg[qt][g], m);
                    float av = __expf(mreg[qt][g] - m_new);
                    mreg[qt][g] = m_new;
                    const int rl = qt * 16 + quad * 4 + g;   // row in 0..31
                    float sum = 0.0f;
#pragma unroll
                    for (int kt = 0; kt < 4; ++kt) {
                        float p = __expf(s[qt][kt][g] - m_new);
                        sum += p;
                        *(_Float16*)(pair + rl * 144 + (kt * 16 + l16) * 2) = (_Float16)p;
                    }
#pragma unroll
                    for (int msk = 1; msk < 16; msk <<= 1) sum += __shfl_xor(sum, msk);
                    lreg[qt][g] = lreg[qt][g] * av + sum;
                    if (l16 == 0) *(float*)(pair + 4608 + rl * 4) = av;
                }
        }
        __syncthreads();   // B3: Ps + alpha ready

        // ---- O rescale + PV over this wave's 256-dv half
        float al[2][4];
#pragma unroll
        for (int qt = 0; qt < 2; ++qt)
#pragma unroll
            for (int g = 0; g < 4; ++g)
                al[qt][g] = *(const float*)(pair + 4608 + (qt * 16 + quad * 4 + g) * 4);
#pragma unroll
        for (int qt = 0; qt < 2; ++qt)
#pragma unroll
            for (int ct = 0; ct < 16; ++ct)
#pragma unroll
                for (int g = 0; g < 4; ++g) oacc[qt][ct][g] *= al[qt][g];

#pragma unroll
        for (int ks = 0; ks < 2; ++ks) {
            f16x8 pa[2];
#pragma unroll
            for (int qt = 0; qt < 2; ++qt)
                pa[qt] = *(const f16x8*)(pair + (qt * 16 + l16) * 144 + (ks * 32 + quad * 8) * 2);
#pragma unroll
            for (int ct = 0; ct < 16; ++ct) {
                int dv = dvh * 256 + ct * 16 + l16;
                int c8 = ks * 4 + quad;
                f16x8 vf = *(const f16x8*)(VtsB + dv * 128 + ((c8 ^ (dv & 7)) << 4));
                oacc[0][ct] = __builtin_amdgcn_mfma_f32_16x16x32_f16(pa[0], vf, oacc[0][ct], 0, 0, 0);
                oacc[1][ct] = __builtin_amdgcn_mfma_f32_16x16x32_f16(pa[1], vf, oacc[1][ct], 0, 0, 0);
            }
        }
        __syncthreads();   // B4: Ks/Vts/Ps consumable -> safe to restage
    }

    // ---- export final l (and M/L partials for the reduce)
    if (kh == 1) {
#pragma unroll
        for (int qt = 0; qt < 2; ++qt)
#pragma unroll
            for (int g = 0; g < 4; ++g) {
                const int rl = qt * 16 + quad * 4 + g;
                if (l16 == 0) {
                    *(float*)(pair + 4608 + rl * 4) = lreg[qt][g];
                    if (nsplit > 1) {
                        int row = qbase + qb * 32 + rl;
                        Mpart[(size_t)blockIdx.y * NQ + row] = mreg[qt][g];
                        Lpart[(size_t)blockIdx.y * NQ + row] = lreg[qt][g];
                    }
                }
            }
    }
    __syncthreads();

    if (nsplit == 1) {
        const float norm = 0.044194173824159216f;
#pragma unroll
        for (int qt = 0; qt < 2; ++qt)
#pragma unroll
            for (int g = 0; g < 4; ++g) {
                const int rl = qt * 16 + quad * 4 + g;
                const float sc = norm / *(const float*)(pair + 4608 + rl * 4);
                const int row = qbase + qb * 32 + rl;
#pragma unroll
                for (int ct = 0; ct < 16; ++ct)
                    outp[(size_t)row * DV + dvh * 256 + ct * 16 + l16] = oacc[qt][ct][g] * sc;
            }
    } else {
        float* op = Opart + (size_t)blockIdx.y * NQ * DV;
#pragma unroll
        for (int qt = 0; qt < 2; ++qt)
#pragma unroll
            for (int g = 0; g < 4; ++g) {
                const int row = qbase + qb * 32 + qt * 16 + quad * 4 + g;
#pragma unroll
                for (int ct = 0; ct < 16; ++ct)
                    op[(size_t)row * DV + dvh * 256 + ct * 16 + l16] = oacc[qt][ct][g];
            }
    }
}

// ---------------- combine KV-split partials -------------------------------
__global__ __launch_bounds__(512) void reduce_kernel(
    const float* __restrict__ Opart, const float* __restrict__ Mpart,
    const float* __restrict__ Lpart, float* __restrict__ outp, int nsplit)
{
    const int tid = threadIdx.x;
    const int row = blockIdx.x * 32 + (tid >> 4);
    const int cb  = (tid & 15) * 4;

    float M = -1e30f;
    for (int s = 0; s < nsplit; ++s)
        M = fmaxf(M, Mpart[(size_t)s * NQ + row]);
    float e[4];
    float L = 0.0f;
    for (int s = 0; s < nsplit; ++s) {
        e[s] = __expf(Mpart[(size_t)s * NQ + row] - M);
        L += Lpart[(size_t)s * NQ + row] * e[s];
    }
    const float r = 0.044194173824159216f / L;

    const float* base = Opart + (size_t)row * DV + cb;
    float* ob = outp + (size_t)row * DV + cb;
#pragma unroll
    for (int i = 0; i < 8; ++i) {
        float4 o = make_float4(0.f, 0.f, 0.f, 0.f);
        for (int s = 0; s < nsplit; ++s) {
            float4 a = *(const float4*)(base + (size_t)s * NQ * DV + i * 64);
            o.x += a.x * e[s]; o.y += a.y * e[s]; o.z += a.z * e[s]; o.w += a.w * e[s];
        }
        o.x *= r; o.y *= r; o.z *= r; o.w *= r;
        *(float4*)(ob + i * 64) = o;
    }
}

extern "C" void kernel_launch(void* const* d_in, const int* in_sizes, int n_in,
                              void* d_out, int out_size, void* d_ws, size_t ws_size,
                              hipStream_t stream) {
    const float* q  = (const float*)d_in[0];
    const float* k  = (const float*)d_in[1];
    const float* v  = (const float*)d_in[2];
    const float* Wq = (const float*)d_in[3];
    const float* bq = (const float*)d_in[4];
    const float* Wk = (const float*)d_in[5];
    const float* bk = (const float*)d_in[6];
    const float* Wv = (const float*)d_in[7];
    const float* bv = (const float*)d_in[8];

    _Float16* Qb = (_Float16*)d_ws;                 // 8 MB
    _Float16* Kb = Qb + (size_t)NQ * DK;            // 8 MB
    _Float16* Vt = Kb + (size_t)NKV * DK;           // 8 MB
    const size_t base = 3 * (size_t)NQ * DK * sizeof(_Float16);
    float* Mpart = (float*)((char*)d_ws + base);           // 4*NQ*4 = 128 KB
    float* Lpart = Mpart + 4 * NQ;                          // 128 KB
    float* Opart = Lpart + 4 * NQ;
    const size_t per_split = (size_t)NQ * DV * sizeof(float);  // 16 MB

    int nsplit = 1;
    if (ws_size >= base + 262144 + 4 * per_split) nsplit = 4;
    else if (ws_size >= base + 262144 + 2 * per_split) nsplit = 2;
    const int nchunks = NKV / (nsplit * BK);
    float* outp = (float*)d_out;

    proj_kernel<<<dim3(DK / 128, NQ / 128, 3), 256, 0, stream>>>(
        q, k, v, Wq, bq, Wk, bk, Wv, bv, Qb, Kb, Vt);
    flash_kernel<<<dim3(NQ / BQ, nsplit), 512, 0, stream>>>(
        Qb, Kb, Vt, Opart, Mpart, Lpart, outp, nsplit, nchunks);
    if (nsplit > 1)
        reduce_kernel<<<dim3(NQ / 32), 512, 0, stream>>>(Opart, Mpart, Lpart, outp, nsplit);
}